// Round 1
// baseline (353.596 us; speedup 1.0000x reference)
//
#include <hip/hip_runtime.h>

// CounterfactualMultiheadAttention — the "uniform counterfactual" makes the
// attention weights independent of Q/K: attn[b,h,q,k] = mask[b,k] ? 0 : 1/cnt[b]
// and ctx[b,q,:] = mean_{k unmasked} V[b,k,:] (same for all q, heads merge).
// By linearity: ctx_row[b] = (sum_masked(value[b])/cnt[b]) @ Wv.T + bv,
//               out_row[b] = ctx_row[b] @ Wo.T + bo, broadcast over q.

#define BATCH 4
#define LSEQ  1024
#define DMOD  1024
#define NHEAD 16
#define HQ    (NHEAD * LSEQ)   // attn rows per batch

// ---------- cnt[b] = max(#unmasked keys, 1) ----------
__global__ void k_cnt(const int* __restrict__ mask, int* __restrict__ cnt) {
    int b = blockIdx.x;
    int local = 0;
    for (int k = threadIdx.x; k < LSEQ; k += 256)
        local += (mask[b * LSEQ + k] == 0);
    __shared__ int sh[256];
    sh[threadIdx.x] = local;
    __syncthreads();
    for (int s = 128; s > 0; s >>= 1) {
        if (threadIdx.x < s) sh[threadIdx.x] += sh[threadIdx.x + s];
        __syncthreads();
    }
    if (threadIdx.x == 0) cnt[b] = max(sh[0], 1);
}

// ---------- vsum[b][d] = sum over unmasked k of value[b,k,d] ----------
// grid (64, B), block 1024 threads (one per d); 16 k's per block; atomicAdd.
__global__ void k_vsum(const float* __restrict__ value,
                       const int* __restrict__ mask,
                       float* __restrict__ vsum) {
    int b = blockIdx.y;
    int d = threadIdx.x;
    int k0 = blockIdx.x * 16;
    float acc = 0.f;
    for (int kk = 0; kk < 16; ++kk) {
        int k = k0 + kk;
        if (mask[b * LSEQ + k] == 0)   // wave-uniform branch (depends on k only)
            acc += value[((size_t)b * LSEQ + k) * DMOD + d];
    }
    atomicAdd(&vsum[b * DMOD + d], acc);
}

// ---------- y[b][o] = scale_b * dot(x[b], W[o]) + bias[o] ----------
// One wave per output column; block = 4 waves; grid (DMOD/4, B).
__global__ void k_matvec(const float* __restrict__ x,     // [B][DMOD]
                         const float* __restrict__ W,     // [DMOD][DMOD], row = out
                         const float* __restrict__ bias,  // [DMOD]
                         const int* __restrict__ cnt,
                         int useInvCnt,
                         float* __restrict__ y) {         // [B][DMOD]
    int b = blockIdx.y;
    int wave = threadIdx.x >> 6;
    int lane = threadIdx.x & 63;
    int o = blockIdx.x * 4 + wave;
    float scale = useInvCnt ? (1.0f / (float)cnt[b]) : 1.0f;
    const float4* x4 = (const float4*)(x + (size_t)b * DMOD);
    const float4* w4 = (const float4*)(W + (size_t)o * DMOD);
    float acc = 0.f;
    for (int i = lane; i < DMOD / 4; i += 64) {
        float4 a = x4[i];
        float4 w = w4[i];
        acc += a.x * w.x + a.y * w.y + a.z * w.z + a.w * w.w;
    }
    for (int off = 32; off > 0; off >>= 1)
        acc += __shfl_down(acc, off, 64);
    if (lane == 0) y[(size_t)b * DMOD + o] = acc * scale + bias[o];
}

// ---------- output[b,q,:] = out_row[b,:] for all q ----------
// grid (LSEQ/16, B), block 256; each thread owns one float4 of the row.
__global__ void k_out(const float* __restrict__ outrow, float* __restrict__ out) {
    int b = blockIdx.y;
    int t = threadIdx.x;
    float4 v = ((const float4*)(outrow + (size_t)b * DMOD))[t];
    float4* base = (float4*)out + ((size_t)b * LSEQ + (size_t)blockIdx.x * 16) * (DMOD / 4) + t;
    #pragma unroll
    for (int r = 0; r < 16; ++r)
        base[(size_t)r * (DMOD / 4)] = v;
}

// ---------- attn[b,h,q,k] = mask[b,k] ? 0 : 1/cnt[b] ----------
// grid (HQ/64, B), block 256; each thread holds its float4 of the row pattern
// in registers and streams 64 rows of coalesced 16B stores.
__global__ void k_attn(const int* __restrict__ mask,
                       const int* __restrict__ cnt,
                       float* __restrict__ attn) {
    int b = blockIdx.y;
    int t = threadIdx.x;
    float inv = 1.0f / (float)cnt[b];
    const int* mrow = mask + (size_t)b * LSEQ;
    float4 pat;
    pat.x = mrow[t * 4 + 0] ? 0.f : inv;
    pat.y = mrow[t * 4 + 1] ? 0.f : inv;
    pat.z = mrow[t * 4 + 2] ? 0.f : inv;
    pat.w = mrow[t * 4 + 3] ? 0.f : inv;
    float4* base = (float4*)attn +
        ((size_t)b * HQ + (size_t)blockIdx.x * 64) * (DMOD / 4) + t;
    #pragma unroll
    for (int r = 0; r < 64; ++r)
        base[(size_t)r * (DMOD / 4)] = pat;
}

extern "C" void kernel_launch(void* const* d_in, const int* in_sizes, int n_in,
                              void* d_out, int out_size, void* d_ws, size_t ws_size,
                              hipStream_t stream) {
    // inputs: 0 query, 1 key, 2 value, 3 key_padding_mask,
    //         4 Wq, 5 bq, 6 Wk, 7 bk, 8 Wv, 9 bv, 10 Wo, 11 bo
    const float* value = (const float*)d_in[2];
    const int*   mask  = (const int*)d_in[3];
    const float* Wv    = (const float*)d_in[8];
    const float* bv    = (const float*)d_in[9];
    const float* Wo    = (const float*)d_in[10];
    const float* bo    = (const float*)d_in[11];

    float* out  = (float*)d_out;                        // [B, L, D]
    float* attn = out + (size_t)BATCH * LSEQ * DMOD;    // [B, H, L, L]

    float* wsf    = (float*)d_ws;
    int*   cnt    = (int*)wsf;                 // 4 ints (padded to 16 floats)
    float* vsum   = wsf + 16;                  // B*D
    float* ctx    = vsum + BATCH * DMOD;       // B*D
    float* outrow = ctx + BATCH * DMOD;        // B*D

    // zero cnt + vsum (workspace is poisoned each call)
    hipMemsetAsync(d_ws, 0, (16 + BATCH * DMOD) * sizeof(float), stream);

    k_cnt   <<<BATCH, 256, 0, stream>>>(mask, cnt);
    k_vsum  <<<dim3(64, BATCH), 1024, 0, stream>>>(value, mask, vsum);
    k_matvec<<<dim3(DMOD / 4, BATCH), 256, 0, stream>>>(vsum, Wv, bv, cnt, 1, ctx);
    k_matvec<<<dim3(DMOD / 4, BATCH), 256, 0, stream>>>(ctx, Wo, bo, cnt, 0, outrow);
    k_out   <<<dim3(LSEQ / 16, BATCH), 256, 0, stream>>>(outrow, out);
    k_attn  <<<dim3(HQ / 64, BATCH), 256, 0, stream>>>(mask, cnt, attn);
}

// Round 3
// 350.610 us; speedup vs baseline: 1.0085x; 1.0085x over previous
//
#include <hip/hip_runtime.h>

// CounterfactualMultiheadAttention — closed form:
//   attn[b,h,q,k] = mask[b,k] ? 0 : 1/cnt[b]          (cnt = #unmasked keys in batch b)
//   out[b,q,:]    = ((sum_{k unmasked} value[b,k,:]) / cnt[b]) @ Wv.T + bv) @ Wo.T + bo
// Q/K/Wq/Wk are never touched. Work = 16 MB read (value), 4 MB x2 read (Wv,Wo),
// 272 MB streamed writes. Store-bound; fill-kernel calibration says 6.3 TB/s is
// achievable for pure stores -> ~50 us floor for the writer.

#define BATCH 4
#define LSEQ  1024
#define DMOD  1024
#define NHEAD 16
#define ROWS_PER_B (NHEAD * LSEQ)       // 16384 attn rows per batch
#define D4    (DMOD / 4)                // 256 float4 per row

typedef float f32x4 __attribute__((ext_vector_type(4)));   // native vec for nontemporal

// ---------- K1: cnt[b] and vsum[b][d] in one pass ----------
// grid (64, B) x 256 threads; block handles 16 k-rows, threads cover the row width.
__global__ void k_vsum(const float* __restrict__ value,
                       const int* __restrict__ mask,
                       float* __restrict__ vsum,   // [B][DMOD], pre-zeroed
                       int* __restrict__ cnt) {    // [B], pre-zeroed
    int b = blockIdx.y;
    int t = threadIdx.x;
    int k0 = blockIdx.x * 16;
    const int* mrow = mask + (size_t)b * LSEQ;
    f32x4 acc = {0.f, 0.f, 0.f, 0.f};
    int c = 0;
    #pragma unroll
    for (int kk = 0; kk < 16; ++kk) {
        int k = k0 + kk;
        if (mrow[k] == 0) {             // wave-uniform branch
            const f32x4* row = (const f32x4*)(value + ((size_t)b * LSEQ + k) * DMOD);
            f32x4 v = row[t];
            acc += v;
            ++c;
        }
    }
    float* dst = vsum + (size_t)b * DMOD + t * 4;
    atomicAdd(dst + 0, acc.x);
    atomicAdd(dst + 1, acc.y);
    atomicAdd(dst + 2, acc.z);
    atomicAdd(dst + 3, acc.w);
    if (t == 0) atomicAdd(&cnt[b], c);
}

// ---------- K2/K3: y[b][o] = scale_b * dot(x[b], W[o]) + bias[o] ----------
// One block per output column o; wave w of the block handles batch w (B==4).
// W row is fetched once per block instead of once per batch.
__global__ void k_matvec(const float* __restrict__ x,     // [B][DMOD]
                         const float* __restrict__ W,     // [DMOD][DMOD] row-major, row=out
                         const float* __restrict__ bias,  // [DMOD]
                         const int* __restrict__ cnt,
                         int useInvCnt,
                         float* __restrict__ y) {         // [B][DMOD]
    int o = blockIdx.x;
    int b = threadIdx.x >> 6;          // wave index == batch
    int lane = threadIdx.x & 63;
    const f32x4* x4 = (const f32x4*)(x + (size_t)b * DMOD);
    const f32x4* w4 = (const f32x4*)(W + (size_t)o * DMOD);
    float acc = 0.f;
    #pragma unroll
    for (int i = lane; i < D4; i += 64) {
        f32x4 a = x4[i];
        f32x4 w = w4[i];
        acc += a.x * w.x + a.y * w.y + a.z * w.z + a.w * w.w;
    }
    #pragma unroll
    for (int off = 32; off > 0; off >>= 1)
        acc += __shfl_down(acc, off, 64);
    if (lane == 0) {
        float scale = useInvCnt ? (1.0f / (float)max(cnt[b], 1)) : 1.0f;
        y[(size_t)b * DMOD + o] = acc * scale + bias[o];
    }
}

// ---------- K4: stream both outputs ----------
// grid (512+32, B) x 256 threads, 32 rows of 4 KB per block, nontemporal stores.
//   bx <  512 : attn rows — pattern[4t+j] = mask[b,4t+j] ? 0 : 1/cnt[b]
//   bx >= 512 : out rows  — broadcast outrow[b]
__global__ void k_write(const int* __restrict__ mask,
                        const int* __restrict__ cnt,
                        const float* __restrict__ outrow,  // [B][DMOD]
                        float* __restrict__ out,           // [B][LSEQ][DMOD]
                        float* __restrict__ attn) {        // [B][ROWS_PER_B][LSEQ]
    int b = blockIdx.y;
    int t = threadIdx.x;
    int bx = blockIdx.x;
    if (bx < 512) {
        float inv = 1.0f / (float)max(cnt[b], 1);
        const int* mrow = mask + (size_t)b * LSEQ;
        f32x4 pat;
        pat.x = mrow[t * 4 + 0] ? 0.f : inv;
        pat.y = mrow[t * 4 + 1] ? 0.f : inv;
        pat.z = mrow[t * 4 + 2] ? 0.f : inv;
        pat.w = mrow[t * 4 + 3] ? 0.f : inv;
        f32x4* base = (f32x4*)attn +
            ((size_t)b * ROWS_PER_B + (size_t)bx * 32) * D4 + t;
        #pragma unroll
        for (int r = 0; r < 32; ++r)
            __builtin_nontemporal_store(pat, base + (size_t)r * D4);
    } else {
        int obx = bx - 512;                       // 0..31 -> 32 rows each = 1024 rows
        f32x4 v = ((const f32x4*)(outrow + (size_t)b * DMOD))[t];
        f32x4* base = (f32x4*)out +
            ((size_t)b * LSEQ + (size_t)obx * 32) * D4 + t;
        #pragma unroll
        for (int r = 0; r < 32; ++r)
            __builtin_nontemporal_store(v, base + (size_t)r * D4);
    }
}

extern "C" void kernel_launch(void* const* d_in, const int* in_sizes, int n_in,
                              void* d_out, int out_size, void* d_ws, size_t ws_size,
                              hipStream_t stream) {
    // inputs: 0 query, 1 key, 2 value, 3 key_padding_mask,
    //         4 Wq, 5 bq, 6 Wk, 7 bk, 8 Wv, 9 bv, 10 Wo, 11 bo
    const float* value = (const float*)d_in[2];
    const int*   mask  = (const int*)d_in[3];
    const float* Wv    = (const float*)d_in[8];
    const float* bv    = (const float*)d_in[9];
    const float* Wo    = (const float*)d_in[10];
    const float* bo    = (const float*)d_in[11];

    float* out  = (float*)d_out;                        // [B, L, D]
    float* attn = out + (size_t)BATCH * LSEQ * DMOD;    // [B, H, L, L]

    float* wsf    = (float*)d_ws;
    int*   cnt    = (int*)wsf;                 // 4 ints (pad to 16 floats)
    float* vsum   = wsf + 16;                  // B*DMOD
    float* ctx    = vsum + BATCH * DMOD;       // B*DMOD
    float* outrow = ctx + BATCH * DMOD;        // B*DMOD

    (void)hipMemsetAsync(d_ws, 0, (16 + BATCH * DMOD) * sizeof(float), stream);

    k_vsum  <<<dim3(64, BATCH), 256, 0, stream>>>(value, mask, vsum, cnt);
    k_matvec<<<DMOD, 256, 0, stream>>>(vsum, Wv, bv, cnt, 1, ctx);
    k_matvec<<<DMOD, 256, 0, stream>>>(ctx, Wo, bo, cnt, 0, outrow);
    k_write <<<dim3(512 + 32, BATCH), 256, 0, stream>>>(mask, cnt, outrow, out, attn);
}